// Round 17
// baseline (309.270 us; speedup 1.0000x reference)
//
#include <hip/hip_runtime.h>

typedef __bf16 bf16x8 __attribute__((ext_vector_type(8)));
typedef float f32x4 __attribute__((ext_vector_type(4)));
typedef unsigned long long u64x2 __attribute__((ext_vector_type(2)));

#define DFEAT 128
#define HDIM 64
#define IDX_BITS 21
#define IDX_MASK ((1u << IDX_BITS) - 1)
#define EMPTY_SLOT 0xFFFFFFFFFFFFFFFFull

// fast shifted-softplus: log(1+e^x) - log2, via native v_exp_f32/v_log_f32
__device__ __forceinline__ float ssp_fast(float x) {
    float m = fmaxf(x, 0.0f);
    float t = __expf(-fabsf(x));
    return m + __logf(1.0f + t) - 0.69314718055994531f;
}

// edge_index may arrive as int32 (harness contract) or int64 (reference dtype).
// Detect at runtime: int64 layout has all-zero odd dwords (values < 2^31).
__global__ void detect_idx_kernel(const unsigned int* __restrict__ p, int n_check,
                                  unsigned int* __restrict__ flag_any) {
    unsigned int acc = 0;
    for (int i = threadIdx.x; i < n_check; i += blockDim.x)
        acc |= p[2 * i + 1];
    if (acc) atomicOr(flag_any, 1u);
}

__device__ __forceinline__ int load_idx(const void* p, int is64, long long i) {
    if (is64) return (int)((const long long*)p)[i];
    return ((const int*)p)[i];
}

// bf16 convert of 8 floats from two f32x4s — static indices only.
#define CVT8H(P, Q, H) do { \
    H[0] = (__bf16)P[0]; H[1] = (__bf16)P[1]; H[2] = (__bf16)P[2]; H[3] = (__bf16)P[3]; \
    H[4] = (__bf16)Q[0]; H[5] = (__bf16)Q[1]; H[6] = (__bf16)Q[2]; H[7] = (__bf16)Q[3]; \
} while (0)

#define MF(A, B, C) __builtin_amdgcn_mfma_f32_16x16x32_bf16(A, B, C, 0, 0, 0)

// One K-chunk (32 of 128): convert A, 1 MFMA per N-tile (pure bf16; absmax
// 0.031 vs 0.1406 threshold, measured rounds 6/9/10/11/13/14/16).
#define KSTEP(P, Q, KT) do { \
    bf16x8 h, bh; \
    CVT8H(P, Q, h); \
    bh = hiTab[((KT)*4 + 0) * 64 + lane]; acc0 = MF(h, bh, acc0); \
    bh = hiTab[((KT)*4 + 1) * 64 + lane]; acc1 = MF(h, bh, acc1); \
    bh = hiTab[((KT)*4 + 2) * 64 + lane]; acc2 = MF(h, bh, acc2); \
    bh = hiTab[((KT)*4 + 3) * 64 + lane]; acc3 = MF(h, bh, acc3); \
} while (0)

// row-slice ssp + w2 dot + 16-lane reduce for C-row j (compile-time J).
#define REDJ(J, OUT) do { \
    float z0 = acc0[J] + b1v0, z1 = acc1[J] + b1v1; \
    float z2 = acc2[J] + b1v2, z3 = acc3[J] + b1v3; \
    float t = ssp_fast(z0) * w2v0 + ssp_fast(z1) * w2v1 \
            + ssp_fast(z2) * w2v2 + ssp_fast(z3) * w2v3; \
    t += __shfl_xor(t, 1); t += __shfl_xor(t, 2); \
    t += __shfl_xor(t, 4); t += __shfl_xor(t, 8); \
    OUT = t; \
} while (0)

// Kernel A: per-edge MLP via bf16 MFMA (round-6 core, nontemporal loads) +
// FUSED scatter-mean accumulation in the epilogue. Rounds 7/8 failed here
// because cross-lane shuffles ran inside the divergent if(leader) branch
// (UB on HIP — reads inactive lanes). This version executes EVERY cross-lane
// op (shfl_up scan, ballot, run-total shfl) unconditionally wave-uniform;
// only the atomicAdds are predicated. Invalid lanes contribute 0, never lead.
// __launch_bounds__(256,4) = cap 128: caps 85 (r10) and 102 (r15) both
// spill catastrophically — the kernel needs >102 VGPRs. Do not cap tighter.
__global__ __launch_bounds__(256, 4) void mlp_mag_kernel(
    const float* __restrict__ feats,
    const void* __restrict__ eidx,
    const float* __restrict__ w1,
    const float* __restrict__ b1,
    const float* __restrict__ w2,
    const float* __restrict__ b2,
    float* __restrict__ mag_raw,
    float* __restrict__ csum,
    float* __restrict__ ccnt,
    const unsigned int* __restrict__ flag_any,
    int E)
{
    __shared__ __align__(16) unsigned char smem[32768];
    float* w1s = (float*)smem;                 // transient: raw w1 (32 KB)
    bf16x8* hiTab = (bf16x8*)smem;             // final: bf16 frags (16 KB)

    const int is64 = (flag_any[0] == 0u) ? 1 : 0;
    const int lane = threadIdx.x & 63;
    const int r = lane & 15;
    const int g = lane >> 4;
    const int wave = blockIdx.x * (blockDim.x >> 6) + (threadIdx.x >> 6);
    const int nwaves = gridDim.x * (blockDim.x >> 6);

    // Stage B fragment table in LDS (once per block).
    for (int idx = threadIdx.x; idx < DFEAT * HDIM / 4; idx += blockDim.x)
        ((float4*)w1s)[idx] = ((const float4*)w1)[idx];
    __syncthreads();
    {
        const int tkt = threadIdx.x >> 6;      // this thread builds frags for k-chunk tkt
        const int tl = threadIdx.x & 63;
        const int tg = tl >> 4, tr = tl & 15;
        float vals[4][8];
#pragma unroll
        for (int nt = 0; nt < 4; ++nt)
#pragma unroll
            for (int i = 0; i < 8; ++i)
                vals[nt][i] = w1s[(tkt * 32 + tg * 8 + i) * HDIM + nt * 16 + tr];
        __syncthreads();                        // done reading raw w1; safe to overwrite
#pragma unroll
        for (int nt = 0; nt < 4; ++nt) {
            bf16x8 h;
#pragma unroll
            for (int i = 0; i < 8; ++i) h[i] = (__bf16)vals[nt][i];
            hiTab[(tkt * 4 + nt) * 64 + tl] = h;
        }
        __syncthreads();
    }

    const float b1v0 = b1[0 * 16 + r], b1v1 = b1[1 * 16 + r];
    const float b1v2 = b1[2 * 16 + r], b1v3 = b1[3 * 16 + r];
    const float w2v0 = w2[0 * 16 + r], w2v1 = w2[1 * 16 + r];
    const float w2v2 = w2[2 * 16 + r], w2v3 = w2[3 * 16 + r];
    const float b2v = b2[0];

    const int ntiles = (E + 15) >> 4;
    for (int tile = wave; tile < ntiles; tile += nwaves) {
        const int e0 = tile << 4;
        int er = e0 + r;
        if (er >= E) er = E - 1;           // clamp: loads stay valid; stores guarded

        const f32x4* fp = (const f32x4*)(feats + (size_t)er * DFEAT) + g * 2;
        f32x4 p0 = __builtin_nontemporal_load(fp + 0);
        f32x4 p1 = __builtin_nontemporal_load(fp + 1);
        f32x4 p2 = __builtin_nontemporal_load(fp + 8);
        f32x4 p3 = __builtin_nontemporal_load(fp + 9);
        f32x4 p4 = __builtin_nontemporal_load(fp + 16);
        f32x4 p5 = __builtin_nontemporal_load(fp + 17);
        f32x4 p6 = __builtin_nontemporal_load(fp + 24);
        f32x4 p7 = __builtin_nontemporal_load(fp + 25);

        f32x4 acc0 = {0.f,0.f,0.f,0.f}, acc1 = {0.f,0.f,0.f,0.f};
        f32x4 acc2 = {0.f,0.f,0.f,0.f}, acc3 = {0.f,0.f,0.f,0.f};
        KSTEP(p0, p1, 0);
        KSTEP(p2, p3, 1);
        KSTEP(p4, p5, 2);
        KSTEP(p6, p7, 3);

        float s0, s1, s2, s3;
        REDJ(0, s0); REDJ(1, s1); REDJ(2, s2); REDJ(3, s3);
        // group g's lanes all hold s0..s3 = raw dots for edges e0+g*4+{0..3}

        // Transpose so lane L (<16) holds edge e0+L: pull from group L>>2.
        int src = ((lane & 15) >> 2) * 16;           // wave-uniform pattern
        float v0 = __shfl(s0, src), v1 = __shfl(s1, src);
        float v2 = __shfl(s2, src), v3 = __shfl(s3, src);
        int jj = lane & 3;
        float m = ((jj == 0) ? v0 : (jj == 1) ? v1 : (jj == 2) ? v2 : v3) + b2v;

        int e = e0 + lane;                           // meaningful for lane<16
        bool valid = (lane < 16) && (e < E);
        int c = valid ? load_idx(eidx, is64, e) : -1;
        if (valid) mag_raw[e] = m;                   // coalesced 64-B store

        // Segmented sum by center-run over lanes 0..15 — ALL cross-lane ops
        // unconditional (lanes>=16 compute unused duplicates; invalid -> 0).
        float mm = valid ? m : 0.0f;
        float ps = mm;
        float t1 = __shfl_up(ps, 1, 16); if ((lane & 15) >= 1) ps += t1;
        float t2 = __shfl_up(ps, 2, 16); if ((lane & 15) >= 2) ps += t2;
        float t4 = __shfl_up(ps, 4, 16); if ((lane & 15) >= 4) ps += t4;
        float t8 = __shfl_up(ps, 8, 16); if ((lane & 15) >= 8) ps += t8;
        int cprev = __shfl_up(c, 1, 16);
        bool leader = valid && ((lane & 15) == 0 || c != cprev);
        unsigned long long lead = __ballot(leader);  // bits >=16 are 0
        unsigned int lead16 = (unsigned int)lead & 0xFFFFu;
        unsigned int above = lead16 >> ((lane & 15) + 1);
        int nxt = above ? ((lane & 15) + 1 + __builtin_ctz(above)) : 16;
        int lim = min(16, E - e0);
        if (nxt > lim) nxt = lim;
        if (nxt < 1) nxt = 1;
        float total = __shfl(ps, nxt - 1, 16);       // UNCONDITIONAL
        float runsum = total - (ps - mm);
        int cnt = nxt - (lane & 15);
        if (leader) {
            atomicAdd(&csum[c], runsum);
            atomicAdd(&ccnt[c], (float)cnt);
        }
    }
}

// Shared key computation. KEY EXACTNESS INVARIANT: bitwise identical to the
// reference (f32 division vec/l, fabs, (x+y)+z, 1e10f mult, trunc) — the
// dataset's no-collision guarantee is defined w.r.t. reference keys.
__device__ __forceinline__ long long edge_key(const float* vec, float l,
                                              int i, int ci, int ni,
                                              float& ux, float& uy, float& uz) {
    ux = vec[3 * i + 0] / l;
    uy = vec[3 * i + 1] / l;
    uz = vec[3 * i + 2] / l;
    float s3 = (fabsf(ux) + fabsf(uy)) + fabsf(uz);
    return (long long)ci + (long long)ni
         + (long long)(1.0e10f * l)
         + (long long)(1.0e10f * s3);
}

// Kernel C1 (INSERT phase): edges with center<neigh (exactly one per
// undirected pair; no self-edges by construction) CAS-claim a 16-byte slot
// and plain-store their DEBIASED magnitude as the payload. No reader exists
// inside this kernel, so there is no handshake (round 12's intra-kernel
// spin deadlocked; the kernel boundary is the release point here).
__global__ __launch_bounds__(256) void insert_kernel(
    const float* __restrict__ vec,
    const float* __restrict__ len,
    const void* __restrict__ eidx,
    const float* __restrict__ mag,
    const float* __restrict__ csum,
    const float* __restrict__ ccnt,
    unsigned long long* __restrict__ tab,   // 2 qwords per slot
    const unsigned int* __restrict__ flag_any,
    int E, int hash_bits)
{
    int i = blockIdx.x * blockDim.x + threadIdx.x;
    if (i >= E) return;
    const int is64 = (flag_any[0] == 0u) ? 1 : 0;

    int ci_ = load_idx(eidx, is64, i);
    int ni_ = load_idx(eidx, is64, (long long)E + i);
    if (ci_ >= ni_) return;                 // finder role handles these

    float ux, uy, uz;
    long long key = edge_key(vec, len[i], i, ci_, ni_, ux, uy, uz);
    float mi = mag[i] - csum[ci_] / fmaxf(ccnt[ci_], 1.0f);

    unsigned long long entry = ((unsigned long long)key << IDX_BITS) | (unsigned)i;
    unsigned long long h = (unsigned long long)key * 0x9E3779B97F4A7C15ull;
    unsigned slot = (unsigned)(h >> (64 - hash_bits));
    const unsigned smask = (1u << hash_bits) - 1u;

    while (true) {
        unsigned long long old = atomicCAS(&tab[2 * (size_t)slot], EMPTY_SLOT, entry);
        if (old == EMPTY_SLOT) {
            *(unsigned int*)(tab + 2 * (size_t)slot + 1) = __float_as_uint(mi);
            return;
        }
        slot = (slot + 1) & smask;
    }
}

// Kernel C2 (FIND phase): edges with center>neigh probe with PLAIN 16-byte
// loads (no CAS). Linear-probing invariant: every slot from h(key) to the
// partner's slot was occupied when the partner inserted, and occupancy only
// grows -> the finder never meets EMPTY before its key. Key + partner index
// + partner payload arrive in ONE cache line. Partner's unit vector is
// EXACTLY -u (vec[j]==-vec[i], len[j]==len[i] bitwise; proven round 9):
// write both edges' forces to non-atomic fscr (each edge written once).
__global__ __launch_bounds__(256) void find_kernel(
    const float* __restrict__ vec,
    const float* __restrict__ len,
    const void* __restrict__ eidx,
    const float* __restrict__ mag,
    const float* __restrict__ csum,
    const float* __restrict__ ccnt,
    const unsigned long long* __restrict__ tab,
    float* __restrict__ fscr,
    const unsigned int* __restrict__ flag_any,
    int E, int hash_bits)
{
    int i = blockIdx.x * blockDim.x + threadIdx.x;
    if (i >= E) return;
    const int is64 = (flag_any[0] == 0u) ? 1 : 0;

    int ci_ = load_idx(eidx, is64, i);
    int ni_ = load_idx(eidx, is64, (long long)E + i);
    if (ci_ <= ni_) return;                 // inserter role handled these

    float ux, uy, uz;
    long long key = edge_key(vec, len[i], i, ci_, ni_, ux, uy, uz);
    float mi = mag[i] - csum[ci_] / fmaxf(ccnt[ci_], 1.0f);

    unsigned long long h = (unsigned long long)key * 0x9E3779B97F4A7C15ull;
    unsigned slot = (unsigned)(h >> (64 - hash_bits));
    const unsigned smask = (1u << hash_bits) - 1u;
    const u64x2* t2 = (const u64x2*)tab;

    int j = -1;
    float mj = 0.0f;
    int guard = (int)smask + 1;             // safety: surface error, never hang
    while (guard-- > 0) {
        u64x2 e = t2[slot];
        if ((e[0] >> IDX_BITS) == (unsigned long long)key) {
            j = (int)(e[0] & IDX_MASK);
            mj = __uint_as_float((unsigned int)(e[1] & 0xFFFFFFFFull));
            break;
        }
        slot = (slot + 1) & smask;
    }
    if (j < 0) return;                      // unreachable if invariants hold

    float avg = 0.5f * (mi + mj);
    float fx = avg * ux, fy = avg * uy, fz = avg * uz;
    fscr[3 * i + 0] = fx;   fscr[3 * i + 1] = fy;   fscr[3 * i + 2] = fz;
    fscr[3 * j + 0] = -fx;  fscr[3 * j + 1] = -fy;  fscr[3 * j + 2] = -fz;
}

// Kernel D: segment-sum of fscratch by (sorted) center via run detection;
// ~3 atomics per run (round-9 proved per-edge scattered atomics cost ~250us).
__global__ __launch_bounds__(256) void force_kernel(
    const float* __restrict__ fscr,
    const void* __restrict__ eidx,
    float* __restrict__ out,
    const unsigned int* __restrict__ flag_any,
    int E)
{
    __shared__ int cs[256];
    __shared__ float fx[256], fy[256], fz[256];
    const int is64 = (flag_any[0] == 0u) ? 1 : 0;
    const int tloc = threadIdx.x;
    const int i = blockIdx.x * 256 + tloc;
    int c = -1;
    if (i < E) {
        c = load_idx(eidx, is64, i);
        fx[tloc] = fscr[3 * i + 0];
        fy[tloc] = fscr[3 * i + 1];
        fz[tloc] = fscr[3 * i + 2];
    }
    cs[tloc] = c;
    __syncthreads();
    if (i < E) {
        bool leader = (tloc == 0) || (cs[tloc - 1] != c);
        if (leader) {
            float sx = 0.f, sy = 0.f, sz = 0.f;
            int j = tloc;
            int lim = min(256, E - blockIdx.x * 256);
            while (j < lim && cs[j] == c) { sx += fx[j]; sy += fy[j]; sz += fz[j]; ++j; }
            atomicAdd(&out[c * 3 + 0], sx);
            atomicAdd(&out[c * 3 + 1], sy);
            atomicAdd(&out[c * 3 + 2], sz);
        }
    }
}

extern "C" void kernel_launch(void* const* d_in, const int* in_sizes, int n_in,
                              void* d_out, int out_size, void* d_ws, size_t ws_size,
                              hipStream_t stream) {
    const float* feats = (const float*)d_in[0];
    const float* vec   = (const float*)d_in[1];
    const float* len   = (const float*)d_in[2];
    const void*  eidx  = d_in[3];
    const float* w1 = (const float*)d_in[4];
    const float* b1 = (const float*)d_in[5];
    const float* w2 = (const float*)d_in[6];
    const float* b2 = (const float*)d_in[7];
    float* out = (float*)d_out;

    const int E = in_sizes[0] / DFEAT;
    const int N = out_size / 3;

    // Workspace: mag(E) | csum(N) | ccnt(N) | flag(256B) | fscr(3E) | tab(16B/slot)
    char* ws = (char*)d_ws;
    size_t off_mag  = 0;
    size_t off_csum = (off_mag + (size_t)E * 4 + 255) & ~(size_t)255;
    size_t off_ccnt = off_csum + (size_t)N * 4;
    size_t off_flag = (off_ccnt + (size_t)N * 4 + 255) & ~(size_t)255;
    size_t off_fscr = off_flag + 256;
    size_t off_tab  = (off_fscr + (size_t)E * 12 + 255) & ~(size_t)255;

    float* mag     = (float*)(ws + off_mag);
    float* csum    = (float*)(ws + off_csum);
    float* ccnt    = (float*)(ws + off_ccnt);
    unsigned int* flag_any = (unsigned int*)(ws + off_flag);
    float* fscr    = (float*)(ws + off_fscr);

    int hash_bits = 21;                 // 16B entries, 800K inserts -> 38% load
    while (hash_bits > 20 && off_tab + (16ull << hash_bits) > ws_size) --hash_bits;
    unsigned long long* tab = (unsigned long long*)(ws + off_tab);

    // one contiguous memset covers csum | ccnt | flag
    hipMemsetAsync(csum, 0, off_flag + 256 - off_csum, stream);
    hipMemsetAsync(tab, 0xFF, (size_t)16 << hash_bits, stream);
    hipMemsetAsync(out, 0, (size_t)out_size * 4, stream);

    int n_check = E < 1024 ? E : 1024;
    detect_idx_kernel<<<1, 256, 0, stream>>>((const unsigned int*)eidx, n_check, flag_any);

    mlp_mag_kernel<<<1024, 256, 0, stream>>>(feats, eidx, w1, b1, w2, b2,
                                             mag, csum, ccnt, flag_any, E);

    int eblocks = (E + 255) / 256;
    insert_kernel<<<eblocks, 256, 0, stream>>>(vec, len, eidx, mag, csum, ccnt,
                                               tab, flag_any, E, hash_bits);
    find_kernel<<<eblocks, 256, 0, stream>>>(vec, len, eidx, mag, csum, ccnt,
                                             tab, fscr, flag_any, E, hash_bits);
    force_kernel<<<eblocks, 256, 0, stream>>>(fscr, eidx, out, flag_any, E);
}

// Round 18
// 304.979 us; speedup vs baseline: 1.0141x; 1.0141x over previous
//
#include <hip/hip_runtime.h>

typedef __bf16 bf16x8 __attribute__((ext_vector_type(8)));
typedef float f32x4 __attribute__((ext_vector_type(4)));
typedef unsigned long long u64x2 __attribute__((ext_vector_type(2)));

#define DFEAT 128
#define HDIM 64
#define IDX_BITS 21
#define IDX_MASK ((1u << IDX_BITS) - 1)
#define EMPTY_SLOT 0xFFFFFFFFFFFFFFFFull

// fast shifted-softplus: log(1+e^x) - log2, via native v_exp_f32/v_log_f32
__device__ __forceinline__ float ssp_fast(float x) {
    float m = fmaxf(x, 0.0f);
    float t = __expf(-fabsf(x));
    return m + __logf(1.0f + t) - 0.69314718055994531f;
}

// edge_index may arrive as int32 (harness contract) or int64 (reference dtype).
// Detect at runtime: int64 layout has all-zero odd dwords (values < 2^31).
__global__ void detect_idx_kernel(const unsigned int* __restrict__ p, int n_check,
                                  unsigned int* __restrict__ flag_any) {
    unsigned int acc = 0;
    for (int i = threadIdx.x; i < n_check; i += blockDim.x)
        acc |= p[2 * i + 1];
    if (acc) atomicOr(flag_any, 1u);
}

__device__ __forceinline__ int load_idx(const void* p, int is64, long long i) {
    if (is64) return (int)((const long long*)p)[i];
    return ((const int*)p)[i];
}

// bf16 convert of 8 floats from two f32x4s — static indices only.
#define CVT8H(P, Q, H) do { \
    H[0] = (__bf16)P[0]; H[1] = (__bf16)P[1]; H[2] = (__bf16)P[2]; H[3] = (__bf16)P[3]; \
    H[4] = (__bf16)Q[0]; H[5] = (__bf16)Q[1]; H[6] = (__bf16)Q[2]; H[7] = (__bf16)Q[3]; \
} while (0)

#define MF(A, B, C) __builtin_amdgcn_mfma_f32_16x16x32_bf16(A, B, C, 0, 0, 0)

// One K-chunk (32 of 128): convert A, 1 MFMA per N-tile (pure bf16; absmax
// 0.031 vs 0.1406 threshold, measured rounds 6/9/10/11/13/14/16/17).
#define KSTEP(P, Q, KT) do { \
    bf16x8 h, bh; \
    CVT8H(P, Q, h); \
    bh = hiTab[((KT)*4 + 0) * 64 + lane]; acc0 = MF(h, bh, acc0); \
    bh = hiTab[((KT)*4 + 1) * 64 + lane]; acc1 = MF(h, bh, acc1); \
    bh = hiTab[((KT)*4 + 2) * 64 + lane]; acc2 = MF(h, bh, acc2); \
    bh = hiTab[((KT)*4 + 3) * 64 + lane]; acc3 = MF(h, bh, acc3); \
} while (0)

// row-slice ssp + w2 dot + 16-lane reduce for C-row j (compile-time J).
#define REDJ(J, OUT) do { \
    float z0 = acc0[J] + b1v0, z1 = acc1[J] + b1v1; \
    float z2 = acc2[J] + b1v2, z3 = acc3[J] + b1v3; \
    float t = ssp_fast(z0) * w2v0 + ssp_fast(z1) * w2v1 \
            + ssp_fast(z2) * w2v2 + ssp_fast(z3) * w2v3; \
    t += __shfl_xor(t, 1); t += __shfl_xor(t, 2); \
    t += __shfl_xor(t, 4); t += __shfl_xor(t, 8); \
    OUT = t; \
} while (0)

// Kernel A: per-edge MLP via bf16 MFMA — round-6 structure + nontemporal
// feature loads. __launch_bounds__(256,4) = VGPR cap 128 is the ONLY safe
// point: caps of 85 (r10) and 102 (r15) both spill catastrophically
// (+100-170 us) — the kernel needs >102 VGPRs. Do not cap tighter.
// Fused-bias epilogue (r17) was correct but net-slower: the scan rides the
// VALU critical path and costs more than bias_kernel's coalesced pass.
__global__ __launch_bounds__(256, 4) void mlp_mag_kernel(
    const float* __restrict__ feats,
    const float* __restrict__ w1,
    const float* __restrict__ b1,
    const float* __restrict__ w2,
    const float* __restrict__ b2,
    float* __restrict__ mag_raw,
    int E)
{
    __shared__ __align__(16) unsigned char smem[32768];
    float* w1s = (float*)smem;                 // transient: raw w1 (32 KB)
    bf16x8* hiTab = (bf16x8*)smem;             // final: bf16 frags (16 KB)

    const int lane = threadIdx.x & 63;
    const int r = lane & 15;
    const int g = lane >> 4;
    const int wave = blockIdx.x * (blockDim.x >> 6) + (threadIdx.x >> 6);
    const int nwaves = gridDim.x * (blockDim.x >> 6);

    // Stage B fragment table in LDS (once per block).
    for (int idx = threadIdx.x; idx < DFEAT * HDIM / 4; idx += blockDim.x)
        ((float4*)w1s)[idx] = ((const float4*)w1)[idx];
    __syncthreads();
    {
        const int tkt = threadIdx.x >> 6;      // this thread builds frags for k-chunk tkt
        const int tl = threadIdx.x & 63;
        const int tg = tl >> 4, tr = tl & 15;
        float vals[4][8];
#pragma unroll
        for (int nt = 0; nt < 4; ++nt)
#pragma unroll
            for (int i = 0; i < 8; ++i)
                vals[nt][i] = w1s[(tkt * 32 + tg * 8 + i) * HDIM + nt * 16 + tr];
        __syncthreads();                        // done reading raw w1; safe to overwrite
#pragma unroll
        for (int nt = 0; nt < 4; ++nt) {
            bf16x8 h;
#pragma unroll
            for (int i = 0; i < 8; ++i) h[i] = (__bf16)vals[nt][i];
            hiTab[(tkt * 4 + nt) * 64 + tl] = h;
        }
        __syncthreads();
    }

    const float b1v0 = b1[0 * 16 + r], b1v1 = b1[1 * 16 + r];
    const float b1v2 = b1[2 * 16 + r], b1v3 = b1[3 * 16 + r];
    const float w2v0 = w2[0 * 16 + r], w2v1 = w2[1 * 16 + r];
    const float w2v2 = w2[2 * 16 + r], w2v3 = w2[3 * 16 + r];
    const float b2v = b2[0];

    const int ntiles = (E + 15) >> 4;
    for (int tile = wave; tile < ntiles; tile += nwaves) {
        const int e0 = tile << 4;
        int er = e0 + r;
        if (er >= E) er = E - 1;           // clamp: loads stay valid; store is guarded

        const f32x4* fp = (const f32x4*)(feats + (size_t)er * DFEAT) + g * 2;
        f32x4 p0 = __builtin_nontemporal_load(fp + 0);
        f32x4 p1 = __builtin_nontemporal_load(fp + 1);
        f32x4 p2 = __builtin_nontemporal_load(fp + 8);
        f32x4 p3 = __builtin_nontemporal_load(fp + 9);
        f32x4 p4 = __builtin_nontemporal_load(fp + 16);
        f32x4 p5 = __builtin_nontemporal_load(fp + 17);
        f32x4 p6 = __builtin_nontemporal_load(fp + 24);
        f32x4 p7 = __builtin_nontemporal_load(fp + 25);

        f32x4 acc0 = {0.f,0.f,0.f,0.f}, acc1 = {0.f,0.f,0.f,0.f};
        f32x4 acc2 = {0.f,0.f,0.f,0.f}, acc3 = {0.f,0.f,0.f,0.f};
        KSTEP(p0, p1, 0);
        KSTEP(p2, p3, 1);
        KSTEP(p4, p5, 2);
        KSTEP(p6, p7, 3);

        float s0, s1, s2, s3;
        REDJ(0, s0); REDJ(1, s1); REDJ(2, s2); REDJ(3, s3);

        if (r < 4) {
            int e = e0 + g * 4 + r;
            if (e < E) {
                // 4-way select by r without a runtime-indexed array (cndmask chain)
                float sel = (r == 0) ? s0 : (r == 1) ? s1 : (r == 2) ? s2 : s3;
                mag_raw[e] = sel + b2v;
            }
        }
    }
}

// Kernel B: scatter-mean sums via sorted-run segmented reduction — round-6
// version (proven). ~2 atomics per center-run; correct even if unsorted.
__global__ __launch_bounds__(256) void bias_kernel(
    const void* __restrict__ eidx,
    const float* __restrict__ mag,
    float* __restrict__ csum,
    float* __restrict__ ccnt,
    const unsigned int* __restrict__ flag_any,
    int E)
{
    __shared__ int cs[256];
    __shared__ float ms[256];
    const int is64 = (flag_any[0] == 0u) ? 1 : 0;
    const int tloc = threadIdx.x;
    const int i = blockIdx.x * 256 + tloc;
    int c = -1; float m = 0.0f;
    if (i < E) { c = load_idx(eidx, is64, i); m = mag[i]; }
    cs[tloc] = c; ms[tloc] = m;
    __syncthreads();
    if (i < E) {
        bool leader = (tloc == 0) || (cs[tloc - 1] != c);
        if (leader) {
            float s = 0.0f; int n = 0; int j = tloc;
            int lim = min(256, E - blockIdx.x * 256);
            while (j < lim && cs[j] == c) { s += ms[j]; ++n; ++j; }
            atomicAdd(&csum[c], s);
            atomicAdd(&ccnt[c], (float)n);
        }
    }
}

// Shared key computation. KEY EXACTNESS INVARIANT: bitwise identical to the
// reference (f32 division vec/l, fabs, (x+y)+z, 1e10f mult, trunc) — the
// dataset's no-collision guarantee is defined w.r.t. reference keys.
__device__ __forceinline__ long long edge_key(const float* vec, float l,
                                              int i, int ci, int ni,
                                              float& ux, float& uy, float& uz) {
    ux = vec[3 * i + 0] / l;
    uy = vec[3 * i + 1] / l;
    uz = vec[3 * i + 2] / l;
    float s3 = (fabsf(ux) + fabsf(uy)) + fabsf(uz);
    return (long long)ci + (long long)ni
         + (long long)(1.0e10f * l)
         + (long long)(1.0e10f * s3);
}

// Kernel C1 (INSERT phase): edges with center<neigh (exactly one per
// undirected pair; no self-edges by construction) CAS-claim a 16-byte slot
// and plain-store their DEBIASED magnitude as the payload. No reader exists
// inside this kernel, so there is no handshake (round 12's intra-kernel
// spin deadlocked; the kernel boundary is the release point here).
// Inserter keys are all distinct -> no key-match check needed on collision.
__global__ __launch_bounds__(256) void insert_kernel(
    const float* __restrict__ vec,
    const float* __restrict__ len,
    const void* __restrict__ eidx,
    const float* __restrict__ mag,
    const float* __restrict__ csum,
    const float* __restrict__ ccnt,
    unsigned long long* __restrict__ tab,   // 2 qwords per slot
    const unsigned int* __restrict__ flag_any,
    int E, int hash_bits)
{
    int i = blockIdx.x * blockDim.x + threadIdx.x;
    if (i >= E) return;
    const int is64 = (flag_any[0] == 0u) ? 1 : 0;

    int ci_ = load_idx(eidx, is64, i);
    int ni_ = load_idx(eidx, is64, (long long)E + i);
    if (ci_ >= ni_) return;                 // finder role handles these

    float ux, uy, uz;
    long long key = edge_key(vec, len[i], i, ci_, ni_, ux, uy, uz);
    float mi = mag[i] - csum[ci_] / fmaxf(ccnt[ci_], 1.0f);

    unsigned long long entry = ((unsigned long long)key << IDX_BITS) | (unsigned)i;
    unsigned long long h = (unsigned long long)key * 0x9E3779B97F4A7C15ull;
    unsigned slot = (unsigned)(h >> (64 - hash_bits));
    const unsigned smask = (1u << hash_bits) - 1u;

    while (true) {
        unsigned long long old = atomicCAS(&tab[2 * (size_t)slot], EMPTY_SLOT, entry);
        if (old == EMPTY_SLOT) {
            *(unsigned int*)(tab + 2 * (size_t)slot + 1) = __float_as_uint(mi);
            return;
        }
        slot = (slot + 1) & smask;
    }
}

// Kernel C2 (FIND phase): edges with center>neigh probe with PLAIN 16-byte
// loads (no CAS). Linear-probing invariant: every slot from h(key) to the
// partner's slot was occupied when the partner inserted, and occupancy only
// grows -> the finder never meets EMPTY before its key. Key + partner index
// + partner payload arrive in ONE cache line. Partner's unit vector is
// EXACTLY -u (vec[j]==-vec[i], len[j]==len[i] bitwise; proven round 9):
// write both edges' forces to non-atomic fscr (each edge written once).
__global__ __launch_bounds__(256) void find_kernel(
    const float* __restrict__ vec,
    const float* __restrict__ len,
    const void* __restrict__ eidx,
    const float* __restrict__ mag,
    const float* __restrict__ csum,
    const float* __restrict__ ccnt,
    const unsigned long long* __restrict__ tab,
    float* __restrict__ fscr,
    const unsigned int* __restrict__ flag_any,
    int E, int hash_bits)
{
    int i = blockIdx.x * blockDim.x + threadIdx.x;
    if (i >= E) return;
    const int is64 = (flag_any[0] == 0u) ? 1 : 0;

    int ci_ = load_idx(eidx, is64, i);
    int ni_ = load_idx(eidx, is64, (long long)E + i);
    if (ci_ <= ni_) return;                 // inserter role handled these

    float ux, uy, uz;
    long long key = edge_key(vec, len[i], i, ci_, ni_, ux, uy, uz);
    float mi = mag[i] - csum[ci_] / fmaxf(ccnt[ci_], 1.0f);

    unsigned long long h = (unsigned long long)key * 0x9E3779B97F4A7C15ull;
    unsigned slot = (unsigned)(h >> (64 - hash_bits));
    const unsigned smask = (1u << hash_bits) - 1u;
    const u64x2* t2 = (const u64x2*)tab;

    int j = -1;
    float mj = 0.0f;
    int guard = (int)smask + 1;             // safety: surface error, never hang
    while (guard-- > 0) {
        u64x2 e = t2[slot];
        if ((e[0] >> IDX_BITS) == (unsigned long long)key) {
            j = (int)(e[0] & IDX_MASK);
            mj = __uint_as_float((unsigned int)(e[1] & 0xFFFFFFFFull));
            break;
        }
        slot = (slot + 1) & smask;
    }
    if (j < 0) return;                      // unreachable if invariants hold

    float avg = 0.5f * (mi + mj);
    float fx = avg * ux, fy = avg * uy, fz = avg * uz;
    fscr[3 * i + 0] = fx;   fscr[3 * i + 1] = fy;   fscr[3 * i + 2] = fz;
    fscr[3 * j + 0] = -fx;  fscr[3 * j + 1] = -fy;  fscr[3 * j + 2] = -fz;
}

// Kernel D: segment-sum of fscratch by (sorted) center via run detection;
// ~3 atomics per run (round-9 proved per-edge scattered atomics cost ~250us).
__global__ __launch_bounds__(256) void force_kernel(
    const float* __restrict__ fscr,
    const void* __restrict__ eidx,
    float* __restrict__ out,
    const unsigned int* __restrict__ flag_any,
    int E)
{
    __shared__ int cs[256];
    __shared__ float fx[256], fy[256], fz[256];
    const int is64 = (flag_any[0] == 0u) ? 1 : 0;
    const int tloc = threadIdx.x;
    const int i = blockIdx.x * 256 + tloc;
    int c = -1;
    if (i < E) {
        c = load_idx(eidx, is64, i);
        fx[tloc] = fscr[3 * i + 0];
        fy[tloc] = fscr[3 * i + 1];
        fz[tloc] = fscr[3 * i + 2];
    }
    cs[tloc] = c;
    __syncthreads();
    if (i < E) {
        bool leader = (tloc == 0) || (cs[tloc - 1] != c);
        if (leader) {
            float sx = 0.f, sy = 0.f, sz = 0.f;
            int j = tloc;
            int lim = min(256, E - blockIdx.x * 256);
            while (j < lim && cs[j] == c) { sx += fx[j]; sy += fy[j]; sz += fz[j]; ++j; }
            atomicAdd(&out[c * 3 + 0], sx);
            atomicAdd(&out[c * 3 + 1], sy);
            atomicAdd(&out[c * 3 + 2], sz);
        }
    }
}

extern "C" void kernel_launch(void* const* d_in, const int* in_sizes, int n_in,
                              void* d_out, int out_size, void* d_ws, size_t ws_size,
                              hipStream_t stream) {
    const float* feats = (const float*)d_in[0];
    const float* vec   = (const float*)d_in[1];
    const float* len   = (const float*)d_in[2];
    const void*  eidx  = d_in[3];
    const float* w1 = (const float*)d_in[4];
    const float* b1 = (const float*)d_in[5];
    const float* w2 = (const float*)d_in[6];
    const float* b2 = (const float*)d_in[7];
    float* out = (float*)d_out;

    const int E = in_sizes[0] / DFEAT;
    const int N = out_size / 3;

    // Workspace: mag(E) | csum(N) | ccnt(N) | flag(256B) | fscr(3E) | tab(16B/slot)
    char* ws = (char*)d_ws;
    size_t off_mag  = 0;
    size_t off_csum = (off_mag + (size_t)E * 4 + 255) & ~(size_t)255;
    size_t off_ccnt = off_csum + (size_t)N * 4;
    size_t off_flag = (off_ccnt + (size_t)N * 4 + 255) & ~(size_t)255;
    size_t off_fscr = off_flag + 256;
    size_t off_tab  = (off_fscr + (size_t)E * 12 + 255) & ~(size_t)255;

    float* mag     = (float*)(ws + off_mag);
    float* csum    = (float*)(ws + off_csum);
    float* ccnt    = (float*)(ws + off_ccnt);
    unsigned int* flag_any = (unsigned int*)(ws + off_flag);
    float* fscr    = (float*)(ws + off_fscr);

    int hash_bits = 21;                 // 16B entries, 800K inserts -> 38% load
    while (hash_bits > 20 && off_tab + (16ull << hash_bits) > ws_size) --hash_bits;
    unsigned long long* tab = (unsigned long long*)(ws + off_tab);

    // one contiguous memset covers csum | ccnt | flag
    hipMemsetAsync(csum, 0, off_flag + 256 - off_csum, stream);
    hipMemsetAsync(tab, 0xFF, (size_t)16 << hash_bits, stream);
    hipMemsetAsync(out, 0, (size_t)out_size * 4, stream);

    int n_check = E < 1024 ? E : 1024;
    detect_idx_kernel<<<1, 256, 0, stream>>>((const unsigned int*)eidx, n_check, flag_any);

    mlp_mag_kernel<<<1024, 256, 0, stream>>>(feats, w1, b1, w2, b2, mag, E);

    int eblocks = (E + 255) / 256;
    bias_kernel<<<eblocks, 256, 0, stream>>>(eidx, mag, csum, ccnt, flag_any, E);
    insert_kernel<<<eblocks, 256, 0, stream>>>(vec, len, eidx, mag, csum, ccnt,
                                               tab, flag_any, E, hash_bits);
    find_kernel<<<eblocks, 256, 0, stream>>>(vec, len, eidx, mag, csum, ccnt,
                                             tab, fscr, flag_any, E, hash_bits);
    force_kernel<<<eblocks, 256, 0, stream>>>(fscr, eidx, out, flag_any, E);
}